// Round 1
// baseline (2223.646 us; speedup 1.0000x reference)
//
#include <hip/hip_runtime.h>

// MHA-no-softmax: out = (rope(XWq+bq) · rope(XWk+bk)ᵀ / B) · (XWv+bv)
// Re-associated as Q · (KᵀV) since there is no softmax:
//   1. proj K (rope) -> d_out (scratch; dead before final store)
//   2. proj V        -> ws[0:64MB)
//   3. M_b = K_bᵀ V_b  (per batch, 1024x1024) -> ws[64MB:80MB)
//   4. proj Q (rope) -> ws[0:64MB)  (V dead after step 3)
//   5. out = Q · M_b * 0.25 -> d_out
// All fp32 vector-FMA tiled GEMMs: 128x128 tile, BK=16, 8x8 per thread.

namespace {
constexpr int kB = 4;
constexpr int kS = 4096;
constexpr int kD = 1024;
constexpr int kBS = kB * kS;       // 16384 rows
constexpr int TILE = 128;
constexpr int BK = 16;
constexpr int LDSW = TILE + 4;     // +4 pad: stride 132 floats (16B-aligned rows)
}  // namespace

#define FMA_8x8(As, Bs)                                                       \
  _Pragma("unroll") for (int kk = 0; kk < BK; ++kk) {                         \
    float4 a0 = *reinterpret_cast<const float4*>(&As[kk][ty * 8]);            \
    float4 a1 = *reinterpret_cast<const float4*>(&As[kk][ty * 8 + 4]);        \
    float4 b0 = *reinterpret_cast<const float4*>(&Bs[kk][tx * 8]);            \
    float4 b1 = *reinterpret_cast<const float4*>(&Bs[kk][tx * 8 + 4]);        \
    const float a[8] = {a0.x, a0.y, a0.z, a0.w, a1.x, a1.y, a1.z, a1.w};      \
    const float b[8] = {b0.x, b0.y, b0.z, b0.w, b1.x, b1.y, b1.z, b1.w};      \
    _Pragma("unroll") for (int i = 0; i < 8; ++i)                             \
        _Pragma("unroll") for (int j = 0; j < 8; ++j)                         \
            acc[i][j] = fmaf(a[i], b[j], acc[i][j]);                          \
  }

// C[m,n] = sum_d X[m,d] * W[n,d] + bias[n]; optional rotary on (even,odd) pairs.
template <bool ROPE>
__global__ __launch_bounds__(256) void proj_kernel(
    const float* __restrict__ X, const float* __restrict__ W,
    const float* __restrict__ bias, const float* __restrict__ fcos,
    const float* __restrict__ fsin, float* __restrict__ Out) {
  __shared__ float Xs[BK][LDSW];
  __shared__ float Ws[BK][LDSW];
  const int tx = threadIdx.x, ty = threadIdx.y;
  const int tid = ty * 16 + tx;
  const int n0 = blockIdx.x * TILE;
  const int m0 = blockIdx.y * TILE;

  // transpose-loader: row lr(+64), k-chunk lc (global contiguous along k)
  const int lr = tid >> 2;         // 0..63
  const int lc = (tid & 3) << 2;   // 0,4,8,12

  float acc[8][8] = {};

  for (int k0 = 0; k0 < kD; k0 += BK) {
#pragma unroll
    for (int it = 0; it < 2; ++it) {
      const int r = lr + it * 64;
      float4 xv = *reinterpret_cast<const float4*>(&X[(m0 + r) * kD + k0 + lc]);
      Xs[lc + 0][r] = xv.x;
      Xs[lc + 1][r] = xv.y;
      Xs[lc + 2][r] = xv.z;
      Xs[lc + 3][r] = xv.w;
      float4 wv = *reinterpret_cast<const float4*>(&W[(n0 + r) * kD + k0 + lc]);
      Ws[lc + 0][r] = wv.x;
      Ws[lc + 1][r] = wv.y;
      Ws[lc + 2][r] = wv.z;
      Ws[lc + 3][r] = wv.w;
    }
    __syncthreads();
    FMA_8x8(Xs, Ws);
    __syncthreads();
  }

  const int gn = n0 + tx * 8;
  float4 bv0 = *reinterpret_cast<const float4*>(&bias[gn]);
  float4 bv1 = *reinterpret_cast<const float4*>(&bias[gn + 4]);
  const float bvals[8] = {bv0.x, bv0.y, bv0.z, bv0.w,
                          bv1.x, bv1.y, bv1.z, bv1.w};
#pragma unroll
  for (int i = 0; i < 8; ++i) {
    const int m = m0 + ty * 8 + i;
    float v[8];
#pragma unroll
    for (int j = 0; j < 8; ++j) v[j] = acc[i][j] + bvals[j];
    if constexpr (ROPE) {
      const int s = m & (kS - 1);
      const int j0 = gn >> 1;  // pair index; 4 consecutive pairs per thread
      float4 c4 = *reinterpret_cast<const float4*>(&fcos[s * (kD / 2) + j0]);
      float4 s4 = *reinterpret_cast<const float4*>(&fsin[s * (kD / 2) + j0]);
      const float cc[4] = {c4.x, c4.y, c4.z, c4.w};
      const float sn[4] = {s4.x, s4.y, s4.z, s4.w};
#pragma unroll
      for (int p = 0; p < 4; ++p) {
        const float h0 = v[2 * p], h1 = v[2 * p + 1];
        v[2 * p] = h0 * cc[p] - h1 * sn[p];
        v[2 * p + 1] = h0 * sn[p] + h1 * cc[p];
      }
    }
    float4 o0 = {v[0], v[1], v[2], v[3]};
    float4 o1 = {v[4], v[5], v[6], v[7]};
    *reinterpret_cast<float4*>(&Out[m * kD + gn]) = o0;
    *reinterpret_cast<float4*>(&Out[m * kD + gn + 4]) = o1;
  }
}

// M_b[i,j] = sum_s K[b,s,i] * V[b,s,j]   (both operands read along contiguous d)
__global__ __launch_bounds__(256) void ktv_kernel(const float* __restrict__ K,
                                                  const float* __restrict__ V,
                                                  float* __restrict__ M) {
  __shared__ float Ks[BK][LDSW];
  __shared__ float Vs[BK][LDSW];
  const int tx = threadIdx.x, ty = threadIdx.y;
  const int tid = ty * 16 + tx;
  const int j0 = blockIdx.x * TILE;
  const int i0 = blockIdx.y * TILE;
  const int b = blockIdx.z;
  const float* Kb = K + (size_t)b * kS * kD;
  const float* Vb = V + (size_t)b * kS * kD;

  const int sr = tid >> 5;         // 0..7 (s-row within chunk)
  const int cc = (tid & 31) << 2;  // 0..124 (col chunk)

  float acc[8][8] = {};
  for (int s0 = 0; s0 < kS; s0 += BK) {
#pragma unroll
    for (int it = 0; it < 2; ++it) {
      const int r = sr + it * 8;
      *reinterpret_cast<float4*>(&Ks[r][cc]) =
          *reinterpret_cast<const float4*>(&Kb[(size_t)(s0 + r) * kD + i0 + cc]);
      *reinterpret_cast<float4*>(&Vs[r][cc]) =
          *reinterpret_cast<const float4*>(&Vb[(size_t)(s0 + r) * kD + j0 + cc]);
    }
    __syncthreads();
    FMA_8x8(Ks, Vs);
    __syncthreads();
  }
  float* Mb = M + (size_t)b * kD * kD;
#pragma unroll
  for (int i = 0; i < 8; ++i) {
    const int gi = i0 + ty * 8 + i;
    float4 o0 = {acc[i][0], acc[i][1], acc[i][2], acc[i][3]};
    float4 o1 = {acc[i][4], acc[i][5], acc[i][6], acc[i][7]};
    *reinterpret_cast<float4*>(&Mb[gi * kD + j0 + tx * 8]) = o0;
    *reinterpret_cast<float4*>(&Mb[gi * kD + j0 + tx * 8 + 4]) = o1;
  }
}

// Out[m,n] = 0.25 * sum_o Q[m,o] * M_b[o,n],  b = m / S
__global__ __launch_bounds__(256) void qm_kernel(const float* __restrict__ Q,
                                                 const float* __restrict__ M,
                                                 float* __restrict__ Out) {
  __shared__ float Qs[BK][LDSW];
  __shared__ float Ms[BK][LDSW];
  const int tx = threadIdx.x, ty = threadIdx.y;
  const int tid = ty * 16 + tx;
  const int n0 = blockIdx.x * TILE;
  const int m0 = blockIdx.y * TILE;
  const float* Mb = M + (size_t)(m0 / kS) * kD * kD;

  const int lr = tid >> 2;         // Q transpose-loader
  const int lc = (tid & 3) << 2;
  const int sr = tid >> 5;         // M direct loader
  const int cc = (tid & 31) << 2;

  float acc[8][8] = {};
  for (int k0 = 0; k0 < kD; k0 += BK) {
#pragma unroll
    for (int it = 0; it < 2; ++it) {
      const int r = lr + it * 64;
      float4 qv = *reinterpret_cast<const float4*>(&Q[(m0 + r) * kD + k0 + lc]);
      Qs[lc + 0][r] = qv.x;
      Qs[lc + 1][r] = qv.y;
      Qs[lc + 2][r] = qv.z;
      Qs[lc + 3][r] = qv.w;
      const int r2 = sr + it * 8;
      *reinterpret_cast<float4*>(&Ms[r2][cc]) =
          *reinterpret_cast<const float4*>(&Mb[(size_t)(k0 + r2) * kD + n0 + cc]);
    }
    __syncthreads();
    FMA_8x8(Qs, Ms);
    __syncthreads();
  }
#pragma unroll
  for (int i = 0; i < 8; ++i) {
    const int m = m0 + ty * 8 + i;
    float4 o0 = {0.25f * acc[i][0], 0.25f * acc[i][1], 0.25f * acc[i][2],
                 0.25f * acc[i][3]};
    float4 o1 = {0.25f * acc[i][4], 0.25f * acc[i][5], 0.25f * acc[i][6],
                 0.25f * acc[i][7]};
    *reinterpret_cast<float4*>(&Out[m * kD + n0 + tx * 8]) = o0;
    *reinterpret_cast<float4*>(&Out[m * kD + n0 + tx * 8 + 4]) = o1;
  }
}

extern "C" void kernel_launch(void* const* d_in, const int* in_sizes, int n_in,
                              void* d_out, int out_size, void* d_ws,
                              size_t ws_size, hipStream_t stream) {
  const float* x = (const float*)d_in[0];
  const float* fcos = (const float*)d_in[1];
  const float* fsin = (const float*)d_in[2];
  const float* wq = (const float*)d_in[3];
  const float* bq = (const float*)d_in[4];
  const float* wk = (const float*)d_in[5];
  const float* bk = (const float*)d_in[6];
  const float* wv = (const float*)d_in[7];
  const float* bv = (const float*)d_in[8];
  float* out = (float*)d_out;

  // Workspace layout (80 MB total):
  float* Vbuf = (float*)d_ws;                                   // 64 MB
  float* Mbuf = (float*)((char*)d_ws + (size_t)kBS * kD * 4);   // 16 MB
  float* Kbuf = out;   // d_out doubles as K scratch (dead before step 5)
  float* Qbuf = Vbuf;  // V dead after ktv -> reuse for Q

  dim3 thr(16, 16);
  dim3 gproj(kD / TILE, kBS / TILE);       // (8, 128)
  dim3 gktv(kD / TILE, kD / TILE, kB);     // (8, 8, 4)
  dim3 gfin(kD / TILE, kBS / TILE);        // (8, 128)

  proj_kernel<true><<<gproj, thr, 0, stream>>>(x, wk, bk, fcos, fsin, Kbuf);
  proj_kernel<false><<<gproj, thr, 0, stream>>>(x, wv, bv, nullptr, nullptr, Vbuf);
  ktv_kernel<<<gktv, thr, 0, stream>>>(Kbuf, Vbuf, Mbuf);
  proj_kernel<true><<<gproj, thr, 0, stream>>>(x, wq, bq, fcos, fsin, Qbuf);
  qm_kernel<<<gfin, thr, 0, stream>>>(Qbuf, Mbuf, out);
}

// Round 5
// 418.193 us; speedup vs baseline: 5.3173x; 5.3173x over previous
//
#include <hip/hip_runtime.h>

// MHA-no-softmax, re-associated:  out = rope(XWq+bq) · [ (rope(XWk+bk))^T (XWv+bv) ] / 4
// f16 MFMA pipeline (fp32 accumulate, rope/bias in fp32):
//   casts: x,wq,wk,wv -> f16
//   projK -> Kt[b][d][s] (d_out lo 32MB)   projV -> Vt[b][d][s] (d_out hi 32MB)
//   ktv  : Mt[b][n][o] = sum_s Vt[n][s]*Kt[o][s]   (split-K=2, fp32 partials + reduce)
//   projQ -> qh[m][d] (ws)
//   qm   : out[m][n] = 0.25 * sum_o qh[m][o]*Mt[n][o]   (fp32 out)
// GEMM core: 128x128 tile, BK=64, 4 waves, mfma_f32_16x16x32_f16,
// global_load_lds width=16 with XOR-swizzled source (rule #21), swizzled ds_read_b128.

typedef _Float16 f16;
typedef _Float16 f16x8 __attribute__((ext_vector_type(8)));
typedef _Float16 f16x4 __attribute__((ext_vector_type(4)));
typedef float f32x4 __attribute__((ext_vector_type(4)));

namespace {
constexpr int kB = 4, kS = 4096, kD = 1024;
constexpr int kBS = kB * kS;  // 16384
constexpr int TM = 128, TN = 128, BK = 64;
enum { EPI_QPROJ, EPI_KPROJ, EPI_VPROJ, EPI_KTV, EPI_QM };
}  // namespace

__device__ __forceinline__ void gld_lds16(const f16* g, f16* l) {
  __builtin_amdgcn_global_load_lds(
      (const __attribute__((address_space(1))) unsigned int*)g,
      (__attribute__((address_space(3))) unsigned int*)l, 16, 0, 0);
}

__global__ void cast_f2h(const float* __restrict__ src, f16* __restrict__ dst,
                         int n) {
  const int stride = gridDim.x * blockDim.x * 8;
  for (int i = (blockIdx.x * blockDim.x + threadIdx.x) * 8; i < n; i += stride) {
    float4 a = *reinterpret_cast<const float4*>(src + i);
    float4 b = *reinterpret_cast<const float4*>(src + i + 4);
    f16x8 o = {(f16)a.x, (f16)a.y, (f16)a.z, (f16)a.w,
               (f16)b.x, (f16)b.y, (f16)b.z, (f16)b.w};
    *reinterpret_cast<f16x8*>(dst + i) = o;
  }
}

// partials p[(b*2+split)][1M] fp32 -> Mt[b][1M] f16
__global__ void reduce_mt(const float* __restrict__ p, f16* __restrict__ mt) {
  const int i = (blockIdx.x * blockDim.x + threadIdx.x) * 8;  // < 4M
  const int b = i >> 20;
  const int w = i & ((1 << 20) - 1);
  const float* p0 = p + ((size_t)(2 * b) << 20) + w;
  const float* p1 = p0 + (1 << 20);
  float4 a0 = *reinterpret_cast<const float4*>(p0);
  float4 a1 = *reinterpret_cast<const float4*>(p0 + 4);
  float4 c0 = *reinterpret_cast<const float4*>(p1);
  float4 c1 = *reinterpret_cast<const float4*>(p1 + 4);
  f16x8 o = {(f16)(a0.x + c0.x), (f16)(a0.y + c0.y), (f16)(a0.z + c0.z),
             (f16)(a0.w + c0.w), (f16)(a1.x + c1.x), (f16)(a1.y + c1.y),
             (f16)(a1.z + c1.z), (f16)(a1.w + c1.w)};
  *reinterpret_cast<f16x8*>(mt + i) = o;
}

template <int EPI, int LDA, int LDB, int KSTEPS>
__global__ __launch_bounds__(256) void gemm_kernel(
    const f16* __restrict__ A, const f16* __restrict__ B,
    const float* __restrict__ bias, const float* __restrict__ fcos,
    const float* __restrict__ fsin, void* __restrict__ Cout) {
  // staging: sA/sB [128][64] f16 (16 KB each); epilogue transpose buf overlaps
  __shared__ __align__(16) unsigned char smem_raw[34816];
  f16* sA = (f16*)smem_raw;
  f16* sB = sA + TM * BK;

  const int tid = threadIdx.x;
  const int w = tid >> 6, lane = tid & 63;
  const int wm = w >> 1, wn = w & 1;
  const int n0 = blockIdx.x * TN;
  const int m0 = blockIdx.y * TM;

  size_t aoff = (size_t)m0 * LDA;
  size_t boff = (size_t)n0 * LDB;
  if constexpr (EPI == EPI_KTV) {
    const int b = blockIdx.z >> 1, sp = blockIdx.z & 1;
    const size_t bo = (size_t)b * kD * kS + (size_t)sp * (kS / 2);
    aoff += bo;
    boff += bo;
  }
  if constexpr (EPI == EPI_QM) boff += (size_t)(m0 >> 12) * kD * kD;
  const f16* Ab = A + aoff;
  const f16* Bb = B + boff;

  const int srow = lane >> 3;          // row within 8-row chunk
  const int scolb = (lane & 7) * 16;   // col bytes within 128B row

  f32x4 acc[4][4];
#pragma unroll
  for (int i = 0; i < 4; ++i)
#pragma unroll
    for (int j = 0; j < 4; ++j) acc[i][j] = (f32x4){0.f, 0.f, 0.f, 0.f};

  for (int ks = 0; ks < KSTEPS; ++ks) {
    const int k0 = ks * BK;
    // stage: wave w loads rows [w*32, w*32+32) of A and B; linear LDS dest,
    // inverse-swizzled global source (involution: colb ^ ((row&7)<<4))
#pragma unroll
    for (int i = 0; i < 4; ++i) {
      const int row = w * 32 + i * 8 + srow;
      const int fe = (scolb ^ ((row & 7) << 4)) >> 1;  // fetch elem offset
      gld_lds16(Ab + (size_t)row * LDA + k0 + fe, sA + w * 2048 + i * 512);
      gld_lds16(Bb + (size_t)row * LDB + k0 + fe, sB + w * 2048 + i * 512);
    }
    __syncthreads();  // compiler drains vmcnt(0) before s_barrier
#pragma unroll
    for (int kc = 0; kc < 2; ++kc) {
      const int clog = kc * 64 + (lane >> 4) * 16;  // logical col bytes
      f16x8 af[4], bf[4];
#pragma unroll
      for (int f = 0; f < 4; ++f) {
        const int ra = wm * 64 + f * 16 + (lane & 15);
        af[f] = *reinterpret_cast<const f16x8*>(
            sA + ra * BK + ((clog ^ ((ra & 7) << 4)) >> 1));
        const int rb = wn * 64 + f * 16 + (lane & 15);
        bf[f] = *reinterpret_cast<const f16x8*>(
            sB + rb * BK + ((clog ^ ((rb & 7) << 4)) >> 1));
      }
#pragma unroll
      for (int i = 0; i < 4; ++i)
#pragma unroll
        for (int j = 0; j < 4; ++j)
          acc[i][j] = __builtin_amdgcn_mfma_f32_16x16x32_f16(af[i], bf[j],
                                                             acc[i][j], 0, 0, 0);
    }
    __syncthreads();
  }

  // C/D layout: row = (lane>>4)*4 + reg, col = lane&15  (per fragment)
  const int rbase = m0 + wm * 64 + (lane >> 4) * 4;
  const int cbase = n0 + wn * 64 + (lane & 15);

  if constexpr (EPI == EPI_KTV) {
    float* C = (float*)Cout + ((size_t)blockIdx.z << 20);
#pragma unroll
    for (int fm = 0; fm < 4; ++fm)
#pragma unroll
      for (int fn = 0; fn < 4; ++fn)
#pragma unroll
        for (int j = 0; j < 4; ++j)
          C[(size_t)(rbase + fm * 16 + j) * kD + cbase + fn * 16] =
              acc[fm][fn][j];
  } else if constexpr (EPI == EPI_QM) {
    float* C = (float*)Cout;
#pragma unroll
    for (int fm = 0; fm < 4; ++fm)
#pragma unroll
      for (int fn = 0; fn < 4; ++fn)
#pragma unroll
        for (int j = 0; j < 4; ++j)
          C[(size_t)(rbase + fm * 16 + j) * kD + cbase + fn * 16] =
              0.25f * acc[fm][fn][j];
  } else {
    // projections: bias (+rope for Q/K) in fp32
#pragma unroll
    for (int fn = 0; fn < 4; ++fn) {
      const int col = cbase + fn * 16;
      const float bv = bias[col];
#pragma unroll
      for (int fm = 0; fm < 4; ++fm)
#pragma unroll
        for (int j = 0; j < 4; ++j) {
          float v = acc[fm][fn][j] + bv;
          if constexpr (EPI == EPI_QPROJ || EPI == EPI_KPROJ) {
            const int s = (rbase + fm * 16 + j) & (kS - 1);
            const int pair = col >> 1;
            const float cc = fcos[s * (kD / 2) + pair];
            const float ss = fsin[s * (kD / 2) + pair];
            const float p = __shfl_xor(v, 1);  // partner col (col^1)
            v = (col & 1) ? (p * ss + v * cc) : (v * cc - p * ss);
          }
          acc[fm][fn][j] = v;
        }
    }
    if constexpr (EPI == EPI_QPROJ) {
      f16* C = (f16*)Cout;
#pragma unroll
      for (int fm = 0; fm < 4; ++fm)
#pragma unroll
        for (int fn = 0; fn < 4; ++fn)
#pragma unroll
          for (int j = 0; j < 4; ++j)
            C[(size_t)(rbase + fm * 16 + j) * kD + cbase + fn * 16] =
                (f16)acc[fm][fn][j];
    } else {
      // K/V: transposed store [b][n][s] via LDS re-stage (coalesced rows)
      f16* tbuf = (f16*)smem_raw;  // [128][136] halves (pad 8 -> benign conflicts)
#pragma unroll
      for (int fm = 0; fm < 4; ++fm)
#pragma unroll
        for (int fn = 0; fn < 4; ++fn) {
          f16x4 pk = {(f16)acc[fm][fn][0], (f16)acc[fm][fn][1],
                      (f16)acc[fm][fn][2], (f16)acc[fm][fn][3]};
          const int rT = wn * 64 + fn * 16 + (lane & 15);      // n-dim
          const int cT = wm * 64 + fm * 16 + (lane >> 4) * 4;  // s-dim
          *reinterpret_cast<f16x4*>(tbuf + rT * 136 + cT) = pk;
        }
      __syncthreads();
      const int bidx = m0 >> 12;
      const int sbase = m0 & (kS - 1);
      f16* Ct = (f16*)Cout + (size_t)bidx * kD * kS + sbase;
#pragma unroll
      for (int it = 0; it < 8; ++it) {
        const int idx = it * 256 + tid;
        const int rn = idx >> 4, ch = idx & 15;
        f16x8 vv = *reinterpret_cast<const f16x8*>(tbuf + rn * 136 + ch * 8);
        *reinterpret_cast<f16x8*>(Ct + (size_t)(n0 + rn) * kS + ch * 8) = vv;
      }
    }
  }
}

extern "C" void kernel_launch(void* const* d_in, const int* in_sizes, int n_in,
                              void* d_out, int out_size, void* d_ws,
                              size_t ws_size, hipStream_t stream) {
  const float* x = (const float*)d_in[0];
  const float* fcos = (const float*)d_in[1];
  const float* fsin = (const float*)d_in[2];
  const float* wq = (const float*)d_in[3];
  const float* bq = (const float*)d_in[4];
  const float* wk = (const float*)d_in[5];
  const float* bk = (const float*)d_in[6];
  const float* wv = (const float*)d_in[7];
  const float* bv = (const float*)d_in[8];

  char* ws = (char*)d_ws;
  f16* xh = (f16*)ws;                              // 32 MiB
  f16* wqh = (f16*)(ws + ((size_t)32 << 20));      // 2 MiB
  f16* wkh = (f16*)(ws + ((size_t)34 << 20));      // 2 MiB
  f16* wvh = (f16*)(ws + ((size_t)36 << 20));      // 2 MiB
  f16* Mt = (f16*)(ws + ((size_t)38 << 20));       // 8 MiB
  float* part = (float*)(ws + ((size_t)46 << 20)); // 32 MiB (dead after reduce)
  f16* qh = (f16*)(ws + ((size_t)46 << 20));       // 32 MiB (aliases part)
  f16* Kt = (f16*)d_out;                           // d_out as scratch (32 MiB)
  f16* Vt = (f16*)d_out + ((size_t)16 << 20);      // (32 MiB)

  dim3 blk(256);
  cast_f2h<<<2048, blk, 0, stream>>>(x, xh, kBS * kD);
  cast_f2h<<<512, blk, 0, stream>>>(wq, wqh, kD * kD);
  cast_f2h<<<512, blk, 0, stream>>>(wk, wkh, kD * kD);
  cast_f2h<<<512, blk, 0, stream>>>(wv, wvh, kD * kD);

  dim3 gproj(kD / TN, kBS / TM);        // (8,128) = 1024 blocks
  dim3 gktv(kD / TN, kD / TM, kB * 2);  // (8,8,8) = 512 blocks (split-K=2)

  gemm_kernel<EPI_KPROJ, kD, kD, kD / BK>
      <<<gproj, blk, 0, stream>>>(xh, wkh, bk, fcos, fsin, Kt);
  gemm_kernel<EPI_VPROJ, kD, kD, kD / BK>
      <<<gproj, blk, 0, stream>>>(xh, wvh, bv, nullptr, nullptr, Vt);
  gemm_kernel<EPI_KTV, kS, kS, (kS / 2) / BK>
      <<<gktv, blk, 0, stream>>>(Vt, Kt, nullptr, nullptr, nullptr, part);
  reduce_mt<<<2048, blk, 0, stream>>>(part, Mt);
  gemm_kernel<EPI_QPROJ, kD, kD, kD / BK>
      <<<gproj, blk, 0, stream>>>(xh, wqh, bq, fcos, fsin, qh);
  gemm_kernel<EPI_QM, kD, kD, kD / BK>
      <<<gproj, blk, 0, stream>>>(qh, Mt, nullptr, nullptr, nullptr,
                                  (float*)d_out);
}